// Round 3
// baseline (382.771 us; speedup 1.0000x reference)
//
#include <hip/hip_runtime.h>
#include <hip/hip_bf16.h>
#include <stdint.h>
#include <math.h>

#define NODES 8192
#define EDGES 4096
#define DIM   128
#define HID   256
#define NHEADS 4

using bf8   = __attribute__((ext_vector_type(8))) short;
using f32x4 = __attribute__((ext_vector_type(4))) float;
using i32x4 = __attribute__((ext_vector_type(4))) int;
using s16x4 = __attribute__((ext_vector_type(4))) short;

__device__ __forceinline__ short f2bf(float f) {
    uint32_t u = __float_as_uint(f);
    u += 0x7fffu + ((u >> 16) & 1u);   // RNE
    return (short)(u >> 16);
}
__device__ __forceinline__ float bf2f(short s) {
    return __uint_as_float(((uint32_t)(unsigned short)s) << 16);
}

// ---- transpose+convert edge_features [4096][128] f32 -> efT [128][4096] bf16
__global__ __launch_bounds__(256) void k_prep_ef(const float* __restrict__ ef, short* __restrict__ efT) {
    __shared__ float tile[32][33];
    int k0 = blockIdx.x * 32, c0 = blockIdx.y * 32;
    int t = threadIdx.x;
#pragma unroll
    for (int i = 0; i < 4; ++i) {
        int idx = t + i * 256;
        int kk = idx >> 5, cc = idx & 31;
        tile[kk][cc] = ef[(size_t)(k0 + kk) * DIM + c0 + cc];
    }
    __syncthreads();
#pragma unroll
    for (int i = 0; i < 4; ++i) {
        int idx = t + i * 256;
        int cc = idx >> 5, kk = idx & 31;
        efT[(size_t)(c0 + cc) * EDGES + k0 + kk] = f2bf(tile[kk][cc]);
    }
}

// ---- node_features f32 -> bf16
__global__ __launch_bounds__(256) void k_prep_x(const float* __restrict__ xf, short* __restrict__ xb) {
    int i = blockIdx.x * 256 + threadIdx.x;   // float4 index, 262144 total
    f32x4 v = *((const f32x4*)xf + i);
    s16x4 o;
#pragma unroll
    for (int j = 0; j < 4; ++j) o[j] = f2bf(v[j]);
    *((s16x4*)xb + i) = o;
}

// ---- fused weights A1T = (Wn@Wo)^T, A2T = (We@Wo)^T (bf16 [h][j][k]); coalesced via LDS chunks
__global__ __launch_bounds__(256) void k_w(const float* __restrict__ Wn, const float* __restrict__ We,
                                           const float* __restrict__ Wo,
                                           short* __restrict__ A1T, short* __restrict__ A2T) {
    __shared__ float lw[2][128][17];
    int b = blockIdx.x, h = b >> 6, jj = b & 63;
    int t = threadIdx.x;
    int mat = t >> 7, k = t & 127;
    const float* WoH = Wo + (size_t)h * HID * DIM;
    float acc0 = 0.f, acc1 = 0.f;
    for (int mc = 0; mc < 16; ++mc) {
        __syncthreads();
#pragma unroll
        for (int i = 0; i < 4; ++i) {
            int u = t + i * 256;
            int m_ = u >> 9, kk2 = (u >> 2) & 127, qd = u & 3;
            const float* src = (m_ ? We : Wn) + (size_t)h * DIM * HID + (size_t)kk2 * HID + mc * 16 + qd * 4;
            f32x4 val = *(const f32x4*)src;
#pragma unroll
            for (int j2 = 0; j2 < 4; ++j2) lw[m_][kk2][qd * 4 + j2] = val[j2];
        }
        __syncthreads();
#pragma unroll
        for (int mm = 0; mm < 16; ++mm) {
            float a = lw[mat][k][mm];
            int m = mc * 16 + mm;
            acc0 += a * WoH[(size_t)m * DIM + jj];
            acc1 += a * WoH[(size_t)m * DIM + jj + 64];
        }
    }
    short* dst = mat ? A2T : A1T;
    dst[(size_t)h * DIM * DIM + (size_t)jj * DIM + k] = f2bf(acc0);
    dst[(size_t)h * DIM * DIM + (size_t)(jj + 64) * DIM + k] = f2bf(acc1);
}

// ---- fused vectors v1=Wn@Wa, v2=We@Wa, u1=bn@Wo+bo, u2=be@Wo, cc={bn@Wa+ba, be@Wa}
__global__ __launch_bounds__(256) void k_wv(const float* __restrict__ Wn, const float* __restrict__ We,
        const float* __restrict__ Wa, const float* __restrict__ bn, const float* __restrict__ be,
        const float* __restrict__ ba, const float* __restrict__ Wo, const float* __restrict__ bo,
        float* __restrict__ v1, float* __restrict__ v2, float* __restrict__ u1, float* __restrict__ u2,
        float* __restrict__ cc) {
    __shared__ float lw[2][128][17];
    int h = blockIdx.x, t = threadIdx.x;
    int mat = t >> 7, k = t & 127;
    const float* wa = Wa + (size_t)h * HID;
    float acc = 0.f;
    for (int mc = 0; mc < 16; ++mc) {
        __syncthreads();
#pragma unroll
        for (int i = 0; i < 4; ++i) {
            int u = t + i * 256;
            int m_ = u >> 9, kk2 = (u >> 2) & 127, qd = u & 3;
            const float* src = (m_ ? We : Wn) + (size_t)h * DIM * HID + (size_t)kk2 * HID + mc * 16 + qd * 4;
            f32x4 val = *(const f32x4*)src;
#pragma unroll
            for (int j2 = 0; j2 < 4; ++j2) lw[m_][kk2][qd * 4 + j2] = val[j2];
        }
        __syncthreads();
#pragma unroll
        for (int mm = 0; mm < 16; ++mm) acc += lw[mat][k][mm] * wa[mc * 16 + mm];
    }
    (mat ? v2 : v1)[h * DIM + k] = acc;
    const float* bias = (mat ? be : bn) + (size_t)h * HID;
    const float* WoH = Wo + (size_t)h * HID * DIM;
    float ua = 0.f;
    for (int m = 0; m < HID; ++m) ua += bias[m] * WoH[(size_t)m * DIM + k];
    if (mat) u2[h * DIM + k] = ua;
    else     u1[h * DIM + k] = ua + bo[h * DIM + k];
    if (t == 0)   { float c = 0.f; for (int m = 0; m < HID; ++m) c += bn[(size_t)h * HID + m] * wa[m]; cc[h * 2 + 0] = c + ba[h]; }
    if (t == 128) { float c = 0.f; for (int m = 0; m < HID; ++m) c += be[(size_t)h * HID + m] * wa[m]; cc[h * 2 + 1] = c; }
}

// ---- P = incidence @ ef : barrier-free register-fragment MFMA, M=32, K-split 2
__global__ __launch_bounds__(256) void k1_pgemm(const float* __restrict__ inc, const short* __restrict__ efT,
        float* __restrict__ Ppart, float* __restrict__ rspart) {
    __shared__ float red[2][32][129];
    __shared__ float rsl[4][2][16];
    const int t = threadIdx.x;
    const int w = t >> 6, l = t & 63, q = l >> 4, lr = l & 15;
    const int m0 = (blockIdx.x >> 1) * 32;
    const int ks = blockIdx.x & 1;
    const int kbase = ks * 2048 + w * 512;
    const float* a0p = inc + (size_t)(m0 + lr) * EDGES + kbase + q * 8;
    const float* a1p = a0p + (size_t)16 * EDGES;
    const short* bbase = efT + (size_t)lr * EDGES + kbase + q * 8;
    f32x4 acc[2][8];
#pragma unroll
    for (int f = 0; f < 2; ++f)
#pragma unroll
        for (int cb = 0; cb < 8; ++cb) acc[f][cb] = (f32x4){0.f, 0.f, 0.f, 0.f};
    float rs0 = 0.f, rs1 = 0.f;
    f32x4 an0 = *(const f32x4*)a0p, an1 = *(const f32x4*)(a0p + 4);
    f32x4 an2 = *(const f32x4*)a1p, an3 = *(const f32x4*)(a1p + 4);
    for (int s = 0; s < 16; ++s) {
        bf8 bfr[8];
        const short* bp = bbase + s * 32;
#pragma unroll
        for (int cb = 0; cb < 8; ++cb) bfr[cb] = *(const bf8*)(bp + cb * 16 * EDGES);
        bf8 a0, a1;
#pragma unroll
        for (int j = 0; j < 4; ++j) {
            a0[j] = f2bf(an0[j]); a0[4 + j] = f2bf(an1[j]);
            a1[j] = f2bf(an2[j]); a1[4 + j] = f2bf(an3[j]);
            rs0 += an0[j] + an1[j];
            rs1 += an2[j] + an3[j];
        }
        if (s < 15) {
            const float* na = a0p + (s + 1) * 32;
            const float* nb = a1p + (s + 1) * 32;
            an0 = *(const f32x4*)na; an1 = *(const f32x4*)(na + 4);
            an2 = *(const f32x4*)nb; an3 = *(const f32x4*)(nb + 4);
        }
#pragma unroll
        for (int cb = 0; cb < 8; ++cb) {
            acc[0][cb] = __builtin_amdgcn_mfma_f32_16x16x32_bf16(a0, bfr[cb], acc[0][cb], 0, 0, 0);
            acc[1][cb] = __builtin_amdgcn_mfma_f32_16x16x32_bf16(a1, bfr[cb], acc[1][cb], 0, 0, 0);
        }
    }
    rs0 += __shfl_xor(rs0, 16); rs0 += __shfl_xor(rs0, 32);
    rs1 += __shfl_xor(rs1, 16); rs1 += __shfl_xor(rs1, 32);
    if (l < 16) { rsl[w][0][lr] = rs0; rsl[w][1][lr] = rs1; }
    if (w < 2) {
#pragma unroll
        for (int f = 0; f < 2; ++f)
#pragma unroll
            for (int cb = 0; cb < 8; ++cb)
#pragma unroll
                for (int r = 0; r < 4; ++r)
                    red[w][f * 16 + q * 4 + r][cb * 16 + lr] = acc[f][cb][r];
    }
    __syncthreads();
    if (w >= 2) {
#pragma unroll
        for (int f = 0; f < 2; ++f)
#pragma unroll
            for (int cb = 0; cb < 8; ++cb)
#pragma unroll
                for (int r = 0; r < 4; ++r)
                    red[w - 2][f * 16 + q * 4 + r][cb * 16 + lr] += acc[f][cb][r];
    }
    __syncthreads();
    float* gp = Ppart + (size_t)ks * (NODES * DIM) + (size_t)m0 * DIM;
#pragma unroll
    for (int i = 0; i < 16; ++i) {
        int e = t + i * 256;
        int row = e >> 7, col = e & 127;
        gp[(size_t)row * DIM + col] = red[0][row][col] + red[1][row][col];
    }
    if (t < 32) {
        int f = t >> 4, r = t & 15;
        rspart[ks * NODES + m0 + f * 16 + r] = rsl[0][f][r] + rsl[1][f][r] + rsl[2][f][r] + rsl[3][f][r];
    }
}

// ---- combine K-split halves: Pbf = bf16(Pa+Pb); rs, invdeg
__global__ __launch_bounds__(256) void k_comb(const float* __restrict__ Ppart, const float* __restrict__ rspart,
        short* __restrict__ Pbf, float* __restrict__ rs, float* __restrict__ idg) {
    int i = blockIdx.x * 256 + threadIdx.x;   // f32x4 index, 262144 total
    f32x4 a = *((const f32x4*)Ppart + i);
    f32x4 b = *((const f32x4*)Ppart + (NODES * DIM / 4) + i);
    s16x4 o;
#pragma unroll
    for (int j = 0; j < 4; ++j) o[j] = f2bf(a[j] + b[j]);
    *((s16x4*)Pbf + i) = o;
    if (blockIdx.x < 32) {
        int idx = blockIdx.x * 256 + threadIdx.x;
        float r = rspart[idx] + rspart[NODES + idx];
        rs[idx] = r;
        idg[idx] = 1.f / (r + 1e-8f);
    }
}

// ---- per-head fused: normalize prev -> x, score+coeff, out GEMM (weights in regs), partial min/max
__global__ __launch_bounds__(256) void k_out(
        const short* __restrict__ xb,      // head 0 input (bf16) or nullptr
        const float* xf,                   // heads>=1: prev outp f32 (aliases outw!)
        const float* __restrict__ smn, const float* __restrict__ srv,
        const short* __restrict__ Pbf, const float* __restrict__ rs, const float* __restrict__ idg,
        const short* __restrict__ W1, const short* __restrict__ W2,
        const float* __restrict__ v1, const float* __restrict__ v2,
        const float* __restrict__ cc, const float* __restrict__ u1, const float* __restrict__ u2,
        float* __restrict__ pmin, float* __restrict__ pmax,
        float* outw) {
    __shared__ short lx[16][136];
    __shared__ short lp[16][136];
    __shared__ float sv1[128], sv2[128], rsL[16], idL[16], coL[16];
    int t = threadIdx.x, m0 = blockIdx.x * 16;
    int w = t >> 6, l = t & 63, q = l >> 4, lr = l & 15;
    // B register fragments straight from global (L2-broadcast across blocks)
    bf8 b1[2][4], b2[2][4];
#pragma unroll
    for (int nf = 0; nf < 2; ++nf) {
        int n = w * 32 + nf * 16 + lr;
#pragma unroll
        for (int kk = 0; kk < 4; ++kk) {
            b1[nf][kk] = *(const bf8*)&W1[(size_t)n * DIM + kk * 32 + q * 8];
            b2[nf][kk] = *(const bf8*)&W2[(size_t)n * DIM + kk * 32 + q * 8];
        }
    }
    {
        int row = t >> 4, c = (t & 15) * 8;
        if (xb) {
            *(i32x4*)&lx[row][c] = *(const i32x4*)&xb[(size_t)(m0 + row) * DIM + c];
        } else {
            f32x4 x0 = *(const f32x4*)&xf[(size_t)(m0 + row) * DIM + c];
            f32x4 x1 = *(const f32x4*)&xf[(size_t)(m0 + row) * DIM + c + 4];
            f32x4 mn0 = *(const f32x4*)&smn[c], mn1 = *(const f32x4*)&smn[c + 4];
            f32x4 rv0 = *(const f32x4*)&srv[c], rv1 = *(const f32x4*)&srv[c + 4];
            bf8 pk;
#pragma unroll
            for (int j = 0; j < 4; ++j) {
                pk[j]     = f2bf(fmaxf((x0[j] - mn0[j]) * rv0[j], 0.f));
                pk[4 + j] = f2bf(fmaxf((x1[j] - mn1[j]) * rv1[j], 0.f));
            }
            *(bf8*)&lx[row][c] = pk;
        }
        *(i32x4*)&lp[row][c] = *(const i32x4*)&Pbf[(size_t)(m0 + row) * DIM + c];
    }
    if (t < 128) { sv1[t] = v1[t]; sv2[t] = v2[t]; }
    if (t < 16) { float r = rs[m0 + t]; rsL[t] = r; idL[t] = idg[m0 + t]; }
    __syncthreads();
    // score -> coeff (threads 0..127: 8 per row)
    if (t < 128) {
        int row = t >> 3, seg = t & 7;
        float id = idL[row];
        float s = 0.f;
#pragma unroll
        for (int j = 0; j < 16; ++j) {
            int c3 = seg * 16 + j;
            s += bf2f(lx[row][c3]) * sv1[c3] + bf2f(lp[row][c3]) * (sv2[c3] * id);
        }
        s += __shfl_xor(s, 1); s += __shfl_xor(s, 2); s += __shfl_xor(s, 4);
        if (seg == 0) {
            float sc = s + cc[0] + rsL[row] * cc[1] * id;
            sc = sc > 0.f ? sc : 0.2f * sc;
            coL[row] = 1.f / (1.f + __expf(-sc));
        }
    }
    f32x4 a1[2] = {{0.f, 0.f, 0.f, 0.f}, {0.f, 0.f, 0.f, 0.f}};
    f32x4 a2[2] = {{0.f, 0.f, 0.f, 0.f}, {0.f, 0.f, 0.f, 0.f}};
#pragma unroll
    for (int kk = 0; kk < 4; ++kk) {
        bf8 xa = *(bf8*)&lx[lr][kk * 32 + q * 8];
        bf8 pa = *(bf8*)&lp[lr][kk * 32 + q * 8];
#pragma unroll
        for (int nf = 0; nf < 2; ++nf) {
            a1[nf] = __builtin_amdgcn_mfma_f32_16x16x32_bf16(xa, b1[nf][kk], a1[nf], 0, 0, 0);
            a2[nf] = __builtin_amdgcn_mfma_f32_16x16x32_bf16(pa, b2[nf][kk], a2[nf], 0, 0, 0);
        }
    }
    __syncthreads();   // coL visible
#pragma unroll
    for (int nf = 0; nf < 2; ++nf) {
        int col = w * 32 + nf * 16 + lr;
        float u1v = u1[col], u2v = u2[col];
        float mnv = 1e30f, mxv = -1e30f;
#pragma unroll
        for (int r = 0; r < 4; ++r) {
            int row = q * 4 + r;
            float cf = coL[row] * idL[row];
            float v = a1[nf][r] + cf * a2[nf][r] + u1v + rsL[row] * cf * u2v;
            outw[(size_t)(m0 + row) * DIM + col] = v;
            mnv = fminf(mnv, v); mxv = fmaxf(mxv, v);
        }
        mnv = fminf(mnv, __shfl_xor(mnv, 16)); mnv = fminf(mnv, __shfl_xor(mnv, 32));
        mxv = fmaxf(mxv, __shfl_xor(mxv, 16)); mxv = fmaxf(mxv, __shfl_xor(mxv, 32));
        if (l < 16) {
            pmin[(size_t)blockIdx.x * DIM + col] = mnv;
            pmax[(size_t)blockIdx.x * DIM + col] = mxv;
        }
    }
}

// ---- reduce 512 per-block partials -> smn, srv (one block)
__global__ __launch_bounds__(256) void k_red(const float* __restrict__ pmin, const float* __restrict__ pmax,
                                             float* __restrict__ smn, float* __restrict__ srv) {
    __shared__ float smnl[2][128], smxl[2][128];
    int t = threadIdx.x, half = t >> 7, c = t & 127;
    float mn = 1e30f, mx = -1e30f;
    for (int b = half * 256; b < half * 256 + 256; ++b) {
        mn = fminf(mn, pmin[(size_t)b * DIM + c]);
        mx = fmaxf(mx, pmax[(size_t)b * DIM + c]);
    }
    smnl[half][c] = mn; smxl[half][c] = mx;
    __syncthreads();
    if (t < 128) {
        float m1 = fminf(smnl[0][t], smnl[1][t]);
        float m2 = fmaxf(smxl[0][t], smxl[1][t]);
        smn[t] = m1;
        srv[t] = 1.f / (m2 - m1 + 1e-8f);
    }
}

// ---- final normalize + relu -> d_out (f32)
__global__ __launch_bounds__(256) void k_fin(const float* __restrict__ outp, const float* __restrict__ smn,
                                             const float* __restrict__ srv, float* __restrict__ dst) {
    int i = blockIdx.x * 256 + threadIdx.x;   // f32x4 index, 262144 total
    f32x4 v = *((const f32x4*)outp + i);
    int c0 = (i & 31) * 4;
    f32x4 mn = *(const f32x4*)&smn[c0], rv = *(const f32x4*)&srv[c0];
#pragma unroll
    for (int j = 0; j < 4; ++j) v[j] = fmaxf((v[j] - mn[j]) * rv[j], 0.f);
    *((f32x4*)dst + i) = v;
}

extern "C" void kernel_launch(void* const* d_in, const int* in_sizes, int n_in,
                              void* d_out, int out_size, void* d_ws, size_t ws_size,
                              hipStream_t stream) {
    const float* nodef = (const float*)d_in[0];
    const float* inc   = (const float*)d_in[1];
    const float* ef    = (const float*)d_in[2];
    const float* Wn    = (const float*)d_in[3];
    const float* bn    = (const float*)d_in[4];
    const float* We    = (const float*)d_in[5];
    const float* be    = (const float*)d_in[6];
    const float* Wa    = (const float*)d_in[7];
    const float* ba    = (const float*)d_in[8];
    const float* Wo    = (const float*)d_in[9];
    const float* bo    = (const float*)d_in[10];

    char* ws = (char*)d_ws;
    float* Ppart  = (float*)(ws);                 // 8 MB
    float* outp   = (float*)(ws + 8388608);       // 4 MB
    short* Pbf    = (short*)(ws + 12582912);      // 2 MB
    short* xb0    = (short*)(ws + 14680064);      // 2 MB
    short* efT    = (short*)(ws + 16777216);      // 1 MB
    short* A1T    = (short*)(ws + 17825792);      // 128 KB
    short* A2T    = (short*)(ws + 17956864);      // 128 KB
    float* rspart = (float*)(ws + 18087936);      // 64 KB
    float* rs     = (float*)(ws + 18153472);      // 32 KB
    float* idg    = (float*)(ws + 18186240);      // 32 KB
    float* v1     = (float*)(ws + 18219008);
    float* v2     = (float*)(ws + 18221056);
    float* u1     = (float*)(ws + 18223104);
    float* u2     = (float*)(ws + 18225152);
    float* cc     = (float*)(ws + 18227200);
    float* smn    = (float*)(ws + 18227264);      // 4x128
    float* srv    = (float*)(ws + 18229312);      // 4x128
    float* pmin   = (float*)(ws + 18231360);      // 512x128
    float* pmax   = (float*)(ws + 18493504);      // 512x128

    hipLaunchKernelGGL(k_prep_ef, dim3(128, 4), dim3(256), 0, stream, ef, efT);
    hipLaunchKernelGGL(k_prep_x, dim3(1024), dim3(256), 0, stream, nodef, xb0);
    hipLaunchKernelGGL(k_w, dim3(256), dim3(256), 0, stream, Wn, We, Wo, A1T, A2T);
    hipLaunchKernelGGL(k_wv, dim3(4), dim3(256), 0, stream, Wn, We, Wa, bn, be, ba, Wo, bo,
                       v1, v2, u1, u2, cc);
    hipLaunchKernelGGL(k1_pgemm, dim3(512), dim3(256), 0, stream, inc, efT, Ppart, rspart);
    hipLaunchKernelGGL(k_comb, dim3(1024), dim3(256), 0, stream, Ppart, rspart, Pbf, rs, idg);

    for (int h = 0; h < NHEADS; ++h) {
        hipLaunchKernelGGL(k_out, dim3(512), dim3(256), 0, stream,
                           (h == 0) ? xb0 : (const short*)nullptr,
                           (h == 0) ? (const float*)nullptr : outp,
                           (h == 0) ? (const float*)nullptr : smn + (h - 1) * DIM,
                           (h == 0) ? (const float*)nullptr : srv + (h - 1) * DIM,
                           Pbf, rs, idg,
                           A1T + (size_t)h * DIM * DIM, A2T + (size_t)h * DIM * DIM,
                           v1 + h * DIM, v2 + h * DIM, cc + h * 2,
                           u1 + h * DIM, u2 + h * DIM,
                           pmin, pmax, outp);
        hipLaunchKernelGGL(k_red, dim3(1), dim3(256), 0, stream,
                           pmin, pmax, smn + h * DIM, srv + h * DIM);
    }
    hipLaunchKernelGGL(k_fin, dim3(1024), dim3(256), 0, stream, outp, smn + 3 * DIM, srv + 3 * DIM,
                       (float*)d_out);
}

// Round 4
// 349.120 us; speedup vs baseline: 1.0964x; 1.0964x over previous
//
#include <hip/hip_runtime.h>
#include <hip/hip_bf16.h>
#include <stdint.h>
#include <math.h>

#define NODES 8192
#define EDGES 4096
#define DIM   128
#define HID   256
#define NHEADS 4

using bf8   = __attribute__((ext_vector_type(8))) short;
using f32x4 = __attribute__((ext_vector_type(4))) float;
using i32x4 = __attribute__((ext_vector_type(4))) int;
using s16x4 = __attribute__((ext_vector_type(4))) short;

__device__ __forceinline__ short f2bf(float f) {
    uint32_t u = __float_as_uint(f);
    u += 0x7fffu + ((u >> 16) & 1u);   // RNE
    return (short)(u >> 16);
}
__device__ __forceinline__ float bf2f(short s) {
    return __uint_as_float(((uint32_t)(unsigned short)s) << 16);
}
// order-preserving float<->uint key for atomic min/max
__device__ __forceinline__ unsigned fkey(float f) {
    unsigned u = __float_as_uint(f);
    return (u & 0x80000000u) ? ~u : (u | 0x80000000u);
}
__device__ __forceinline__ float fdec(unsigned k) {
    unsigned u = (k & 0x80000000u) ? (k & 0x7fffffffu) : ~k;
    return __uint_as_float(u);
}

// ============ k_init: prep_ef + prep_x + fused weights + fused vectors + amin/amax init ============
__global__ __launch_bounds__(256) void k_init(
        const float* __restrict__ ef, short* __restrict__ efT,
        const float* __restrict__ xf, short* __restrict__ xb,
        const float* __restrict__ Wn, const float* __restrict__ We, const float* __restrict__ Wo,
        const float* __restrict__ Wa, const float* __restrict__ bn, const float* __restrict__ be,
        const float* __restrict__ ba, const float* __restrict__ bo,
        short* __restrict__ A1T, short* __restrict__ A2T,
        float* __restrict__ v1, float* __restrict__ v2,
        float* __restrict__ u1, float* __restrict__ u2, float* __restrict__ cc,
        unsigned* __restrict__ amin, unsigned* __restrict__ amax) {
    __shared__ float lw[2][128][17];   // 17408 B; also reused as the 32x33 transpose tile
    int b = blockIdx.x, t = threadIdx.x;

    // ---- transpose+convert edge_features tile (512 tiles = 128 x 4) ----
    {
        float (*tile)[33] = (float(*)[33])lw;
        int k0 = (b & 127) * 32, c0 = (b >> 7) * 32;
#pragma unroll
        for (int i = 0; i < 4; ++i) {
            int idx = t + i * 256;
            int kk = idx >> 5, ccv = idx & 31;
            tile[kk][ccv] = ef[(size_t)(k0 + kk) * DIM + c0 + ccv];
        }
        __syncthreads();
#pragma unroll
        for (int i = 0; i < 4; ++i) {
            int idx = t + i * 256;
            int ccv = idx >> 5, kk = idx & 31;
            efT[(size_t)(c0 + ccv) * EDGES + k0 + kk] = f2bf(tile[kk][ccv]);
        }
        __syncthreads();
    }
    // ---- node_features f32 -> bf16 ----
#pragma unroll
    for (int i = 0; i < 2; ++i) {
        int idx = b * 256 + t + i * 131072;
        f32x4 v = *((const f32x4*)xf + idx);
        s16x4 o;
#pragma unroll
        for (int j = 0; j < 4; ++j) o[j] = f2bf(v[j]);
        *((s16x4*)xb + idx) = o;
    }
    // ---- init atomic min/max slots ----
    if (b == 0) {
#pragma unroll
        for (int i = 0; i < 2; ++i) {
            int u = t + i * 256;
            amin[u] = 0xFFFFFFFFu;
            amax[u] = 0u;
        }
    }

    if (b < 256) {
        // ---- fused weights A1T=(Wn@Wo)^T, A2T=(We@Wo)^T ----
        int h = b >> 6, jj = b & 63;
        int mat = t >> 7, k = t & 127;
        const float* WoH = Wo + (size_t)h * HID * DIM;
        float acc0 = 0.f, acc1 = 0.f;
        for (int mc = 0; mc < 16; ++mc) {
            __syncthreads();
#pragma unroll
            for (int i = 0; i < 4; ++i) {
                int u = t + i * 256;
                int m_ = u >> 9, kk2 = (u >> 2) & 127, qd = u & 3;
                const float* src = (m_ ? We : Wn) + (size_t)h * DIM * HID + (size_t)kk2 * HID + mc * 16 + qd * 4;
                f32x4 val = *(const f32x4*)src;
#pragma unroll
                for (int j2 = 0; j2 < 4; ++j2) lw[m_][kk2][qd * 4 + j2] = val[j2];
            }
            __syncthreads();
#pragma unroll
            for (int mm = 0; mm < 16; ++mm) {
                float a = lw[mat][k][mm];
                int m = mc * 16 + mm;
                acc0 += a * WoH[(size_t)m * DIM + jj];
                acc1 += a * WoH[(size_t)m * DIM + jj + 64];
            }
        }
        short* dst = mat ? A2T : A1T;
        dst[(size_t)h * DIM * DIM + (size_t)jj * DIM + k] = f2bf(acc0);
        dst[(size_t)h * DIM * DIM + (size_t)(jj + 64) * DIM + k] = f2bf(acc1);
    } else if (b < 260) {
        // ---- fused vectors for head h ----
        int h = b - 256;
        int mat = t >> 7, k = t & 127;
        const float* wa = Wa + (size_t)h * HID;
        float acc = 0.f;
        for (int mc = 0; mc < 16; ++mc) {
            __syncthreads();
#pragma unroll
            for (int i = 0; i < 4; ++i) {
                int u = t + i * 256;
                int m_ = u >> 9, kk2 = (u >> 2) & 127, qd = u & 3;
                const float* src = (m_ ? We : Wn) + (size_t)h * DIM * HID + (size_t)kk2 * HID + mc * 16 + qd * 4;
                f32x4 val = *(const f32x4*)src;
#pragma unroll
                for (int j2 = 0; j2 < 4; ++j2) lw[m_][kk2][qd * 4 + j2] = val[j2];
            }
            __syncthreads();
#pragma unroll
            for (int mm = 0; mm < 16; ++mm) acc += lw[mat][k][mm] * wa[mc * 16 + mm];
        }
        (mat ? v2 : v1)[h * DIM + k] = acc;
        const float* bias = (mat ? be : bn) + (size_t)h * HID;
        const float* WoH = Wo + (size_t)h * HID * DIM;
        float ua = 0.f;
        for (int m = 0; m < HID; ++m) ua += bias[m] * WoH[(size_t)m * DIM + k];
        if (mat) u2[h * DIM + k] = ua;
        else     u1[h * DIM + k] = ua + bo[h * DIM + k];
        // cc: parallel 64-lane reductions
        if (t < 64) {
            float c = 0.f;
#pragma unroll
            for (int j = 0; j < 4; ++j) { int m = t + j * 64; c += bn[(size_t)h * HID + m] * wa[m]; }
#pragma unroll
            for (int off = 1; off < 64; off <<= 1) c += __shfl_xor(c, off);
            if (t == 0) cc[h * 2 + 0] = c + ba[h];
        } else if (t < 128) {
            int l2 = t - 64;
            float c = 0.f;
#pragma unroll
            for (int j = 0; j < 4; ++j) { int m = l2 + j * 64; c += be[(size_t)h * HID + m] * wa[m]; }
#pragma unroll
            for (int off = 1; off < 64; off <<= 1) c += __shfl_xor(c, off);
            if (l2 == 0) cc[h * 2 + 1] = c;
        }
    }
}

// ============ k_pgemm: P = incidence @ ef (full K per block), epilogue -> Pbf, rs, idg ============
__global__ __launch_bounds__(256) void k_pgemm(const float* __restrict__ inc, const short* __restrict__ efT,
        short* __restrict__ Pbf, float* __restrict__ rs, float* __restrict__ idg) {
    __shared__ float red[2][32][129];
    __shared__ float rsl[4][2][16];
    const int t = threadIdx.x;
    const int w = t >> 6, l = t & 63, q = l >> 4, lr = l & 15;
    const int m0 = blockIdx.x * 32;
    const int kbase = w * 1024;          // each wave owns K=1024 over 32 steps of 32
    const float* a0p = inc + (size_t)(m0 + lr) * EDGES + kbase + q * 8;
    const float* a1p = a0p + (size_t)16 * EDGES;
    const short* bbase = efT + (size_t)lr * EDGES + kbase + q * 8;
    f32x4 acc[2][8];
#pragma unroll
    for (int f = 0; f < 2; ++f)
#pragma unroll
        for (int cb = 0; cb < 8; ++cb) acc[f][cb] = (f32x4){0.f, 0.f, 0.f, 0.f};
    float rs0 = 0.f, rs1 = 0.f;
    // depth-2 A prefetch ring
    f32x4 an[2][4];
#pragma unroll
    for (int pp = 0; pp < 2; ++pp) {
        an[pp][0] = *(const f32x4*)(a0p + pp * 32);
        an[pp][1] = *(const f32x4*)(a0p + pp * 32 + 4);
        an[pp][2] = *(const f32x4*)(a1p + pp * 32);
        an[pp][3] = *(const f32x4*)(a1p + pp * 32 + 4);
    }
    for (int s = 0; s < 32; ++s) {
        bf8 bfr[8];
        const short* bp = bbase + s * 32;
#pragma unroll
        for (int cb = 0; cb < 8; ++cb) bfr[cb] = *(const bf8*)(bp + cb * 16 * EDGES);
        int ring = s & 1;
        bf8 a0, a1;
#pragma unroll
        for (int j = 0; j < 4; ++j) {
            a0[j] = f2bf(an[ring][0][j]); a0[4 + j] = f2bf(an[ring][1][j]);
            a1[j] = f2bf(an[ring][2][j]); a1[4 + j] = f2bf(an[ring][3][j]);
            rs0 += an[ring][0][j] + an[ring][1][j];
            rs1 += an[ring][2][j] + an[ring][3][j];
        }
        if (s < 30) {
            const float* na = a0p + (s + 2) * 32;
            const float* nb = a1p + (s + 2) * 32;
            an[ring][0] = *(const f32x4*)na; an[ring][1] = *(const f32x4*)(na + 4);
            an[ring][2] = *(const f32x4*)nb; an[ring][3] = *(const f32x4*)(nb + 4);
        }
#pragma unroll
        for (int cb = 0; cb < 8; ++cb) {
            acc[0][cb] = __builtin_amdgcn_mfma_f32_16x16x32_bf16(a0, bfr[cb], acc[0][cb], 0, 0, 0);
            acc[1][cb] = __builtin_amdgcn_mfma_f32_16x16x32_bf16(a1, bfr[cb], acc[1][cb], 0, 0, 0);
        }
    }
    // rowsum: combine q-groups, then cross-wave via LDS
    rs0 += __shfl_xor(rs0, 16); rs0 += __shfl_xor(rs0, 32);
    rs1 += __shfl_xor(rs1, 16); rs1 += __shfl_xor(rs1, 32);
    if (l < 16) { rsl[w][0][lr] = rs0; rsl[w][1][lr] = rs1; }
    if (w < 2) {
#pragma unroll
        for (int f = 0; f < 2; ++f)
#pragma unroll
            for (int cb = 0; cb < 8; ++cb)
#pragma unroll
                for (int r = 0; r < 4; ++r)
                    red[w][f * 16 + q * 4 + r][cb * 16 + lr] = acc[f][cb][r];
    }
    __syncthreads();
    if (w >= 2) {
#pragma unroll
        for (int f = 0; f < 2; ++f)
#pragma unroll
            for (int cb = 0; cb < 8; ++cb)
#pragma unroll
                for (int r = 0; r < 4; ++r)
                    red[w - 2][f * 16 + q * 4 + r][cb * 16 + lr] += acc[f][cb][r];
    }
    __syncthreads();
#pragma unroll
    for (int i = 0; i < 4; ++i) {
        int u = t + i * 256;
        int row = u >> 5, c4 = (u & 31) * 4;
        s16x4 o;
#pragma unroll
        for (int j = 0; j < 4; ++j) o[j] = f2bf(red[0][row][c4 + j] + red[1][row][c4 + j]);
        *(s16x4*)&Pbf[(size_t)(m0 + row) * DIM + c4] = o;
    }
    if (t < 32) {
        int f = t >> 4, r = t & 15;
        float rsv = rsl[0][f][r] + rsl[1][f][r] + rsl[2][f][r] + rsl[3][f][r];
        rs[m0 + f * 16 + r] = rsv;
        idg[m0 + f * 16 + r] = 1.f / (rsv + 1e-8f);
    }
}

// ============ k_out: per-head fused normalize-in + score + GEMM + atomic minmax ============
__global__ __launch_bounds__(256) void k_out(
        const short* __restrict__ xb,      // head 0 input (bf16) or nullptr
        const float* xf,                   // heads>=1: prev outp f32 (aliases outw)
        const unsigned* __restrict__ aminP, const unsigned* __restrict__ amaxP,
        const short* __restrict__ Pbf, const float* __restrict__ rs, const float* __restrict__ idg,
        const short* __restrict__ W1, const short* __restrict__ W2,
        const float* __restrict__ v1, const float* __restrict__ v2,
        const float* __restrict__ cc, const float* __restrict__ u1, const float* __restrict__ u2,
        unsigned* __restrict__ aminC, unsigned* __restrict__ amaxC,
        float* outw) {
    __shared__ short lx[16][136];
    __shared__ short lp[16][136];
    __shared__ float sv1[128], sv2[128], rsL[16], idL[16], coL[16];
    int t = threadIdx.x, m0 = blockIdx.x * 16;
    int w = t >> 6, l = t & 63, q = l >> 4, lr = l & 15;
    // B register fragments straight from global (L2-broadcast)
    bf8 b1[2][4], b2[2][4];
#pragma unroll
    for (int nf = 0; nf < 2; ++nf) {
        int n = w * 32 + nf * 16 + lr;
#pragma unroll
        for (int kk = 0; kk < 4; ++kk) {
            b1[nf][kk] = *(const bf8*)&W1[(size_t)n * DIM + kk * 32 + q * 8];
            b2[nf][kk] = *(const bf8*)&W2[(size_t)n * DIM + kk * 32 + q * 8];
        }
    }
    {
        int row = t >> 4, c = (t & 15) * 8;
        if (xb) {
            *(i32x4*)&lx[row][c] = *(const i32x4*)&xb[(size_t)(m0 + row) * DIM + c];
        } else {
            f32x4 x0 = *(const f32x4*)&xf[(size_t)(m0 + row) * DIM + c];
            f32x4 x1 = *(const f32x4*)&xf[(size_t)(m0 + row) * DIM + c + 4];
            bf8 pk;
#pragma unroll
            for (int j = 0; j < 8; ++j) {
                float mn = fdec(aminP[c + j]);
                float rv = 1.f / (fdec(amaxP[c + j]) - mn + 1e-8f);
                float xv = (j < 4) ? x0[j] : x1[j - 4];
                pk[j] = f2bf(fmaxf((xv - mn) * rv, 0.f));
            }
            *(bf8*)&lx[row][c] = pk;
        }
        *(i32x4*)&lp[row][c] = *(const i32x4*)&Pbf[(size_t)(m0 + row) * DIM + c];
    }
    if (t < 128) { sv1[t] = v1[t]; sv2[t] = v2[t]; }
    if (t < 16) { rsL[t] = rs[m0 + t]; idL[t] = idg[m0 + t]; }
    __syncthreads();
    // score -> coeff (threads 0..127: 8 per row)
    if (t < 128) {
        int row = t >> 3, seg = t & 7;
        float id = idL[row];
        float s = 0.f;
#pragma unroll
        for (int j = 0; j < 16; ++j) {
            int c3 = seg * 16 + j;
            s += bf2f(lx[row][c3]) * sv1[c3] + bf2f(lp[row][c3]) * (sv2[c3] * id);
        }
        s += __shfl_xor(s, 1); s += __shfl_xor(s, 2); s += __shfl_xor(s, 4);
        if (seg == 0) {
            float sc = s + cc[0] + rsL[row] * cc[1] * id;
            sc = sc > 0.f ? sc : 0.2f * sc;
            coL[row] = 1.f / (1.f + __expf(-sc));
        }
    }
    f32x4 a1[2] = {{0.f, 0.f, 0.f, 0.f}, {0.f, 0.f, 0.f, 0.f}};
    f32x4 a2[2] = {{0.f, 0.f, 0.f, 0.f}, {0.f, 0.f, 0.f, 0.f}};
#pragma unroll
    for (int kk = 0; kk < 4; ++kk) {
        bf8 xa = *(bf8*)&lx[lr][kk * 32 + q * 8];
        bf8 pa = *(bf8*)&lp[lr][kk * 32 + q * 8];
#pragma unroll
        for (int nf = 0; nf < 2; ++nf) {
            a1[nf] = __builtin_amdgcn_mfma_f32_16x16x32_bf16(xa, b1[nf][kk], a1[nf], 0, 0, 0);
            a2[nf] = __builtin_amdgcn_mfma_f32_16x16x32_bf16(pa, b2[nf][kk], a2[nf], 0, 0, 0);
        }
    }
    __syncthreads();   // coL visible
#pragma unroll
    for (int nf = 0; nf < 2; ++nf) {
        int col = w * 32 + nf * 16 + lr;
        float u1v = u1[col], u2v = u2[col];
        float mnv = 1e30f, mxv = -1e30f;
#pragma unroll
        for (int r = 0; r < 4; ++r) {
            int row = q * 4 + r;
            float cf = coL[row] * idL[row];
            float v = a1[nf][r] + cf * a2[nf][r] + u1v + rsL[row] * cf * u2v;
            outw[(size_t)(m0 + row) * DIM + col] = v;
            mnv = fminf(mnv, v); mxv = fmaxf(mxv, v);
        }
        mnv = fminf(mnv, __shfl_xor(mnv, 16)); mnv = fminf(mnv, __shfl_xor(mnv, 32));
        mxv = fmaxf(mxv, __shfl_xor(mxv, 16)); mxv = fmaxf(mxv, __shfl_xor(mxv, 32));
        if (l < 16) {
            atomicMin(&aminC[col], fkey(mnv));
            atomicMax(&amaxC[col], fkey(mxv));
        }
    }
}

// ============ k_fin: decode last head's minmax, normalize + relu -> d_out ============
__global__ __launch_bounds__(256) void k_fin(const float* __restrict__ outp,
        const unsigned* __restrict__ amin, const unsigned* __restrict__ amax,
        float* __restrict__ dst) {
    __shared__ float smn[128], srv[128];
    int t = threadIdx.x;
    if (t < 128) {
        float mn = fdec(amin[t]);
        smn[t] = mn;
        srv[t] = 1.f / (fdec(amax[t]) - mn + 1e-8f);
    }
    __syncthreads();
#pragma unroll
    for (int i = 0; i < 2; ++i) {
        int idx = blockIdx.x * 256 + t + i * 131072;
        f32x4 v = *((const f32x4*)outp + idx);
        int c0 = (idx & 31) * 4;
#pragma unroll
        for (int j = 0; j < 4; ++j) v[j] = fmaxf((v[j] - smn[c0 + j]) * srv[c0 + j], 0.f);
        *((f32x4*)dst + idx) = v;
    }
}

extern "C" void kernel_launch(void* const* d_in, const int* in_sizes, int n_in,
                              void* d_out, int out_size, void* d_ws, size_t ws_size,
                              hipStream_t stream) {
    const float* nodef = (const float*)d_in[0];
    const float* inc   = (const float*)d_in[1];
    const float* ef    = (const float*)d_in[2];
    const float* Wn    = (const float*)d_in[3];
    const float* bn    = (const float*)d_in[4];
    const float* We    = (const float*)d_in[5];
    const float* be    = (const float*)d_in[6];
    const float* Wa    = (const float*)d_in[7];
    const float* ba    = (const float*)d_in[8];
    const float* Wo    = (const float*)d_in[9];
    const float* bo    = (const float*)d_in[10];

    char* ws = (char*)d_ws;
    float*    outp = (float*)(ws);                  // 4 MB
    short*    Pbf  = (short*)(ws + 4194304);        // 2 MB
    short*    xb   = (short*)(ws + 6291456);        // 2 MB
    short*    efT  = (short*)(ws + 8388608);        // 1 MB
    short*    A1T  = (short*)(ws + 9437184);        // 128 KB
    short*    A2T  = (short*)(ws + 9568256);        // 128 KB
    float*    rs   = (float*)(ws + 9699328);        // 32 KB
    float*    idg  = (float*)(ws + 9732096);        // 32 KB
    float*    v1   = (float*)(ws + 9764864);
    float*    v2   = (float*)(ws + 9766912);
    float*    u1   = (float*)(ws + 9768960);
    float*    u2   = (float*)(ws + 9771008);
    float*    cc   = (float*)(ws + 9773056);
    unsigned* amin = (unsigned*)(ws + 9775104);     // 4x128
    unsigned* amax = (unsigned*)(ws + 9777152);     // 4x128

    hipLaunchKernelGGL(k_init, dim3(512), dim3(256), 0, stream,
                       ef, efT, nodef, xb, Wn, We, Wo, Wa, bn, be, ba, bo,
                       A1T, A2T, v1, v2, u1, u2, cc, amin, amax);
    hipLaunchKernelGGL(k_pgemm, dim3(256), dim3(256), 0, stream, inc, efT, Pbf, rs, idg);

    for (int h = 0; h < NHEADS; ++h) {
        hipLaunchKernelGGL(k_out, dim3(512), dim3(256), 0, stream,
                           (h == 0) ? xb : (const short*)nullptr,
                           (h == 0) ? (const float*)nullptr : outp,
                           (h == 0) ? (const unsigned*)nullptr : amin + (h - 1) * DIM,
                           (h == 0) ? (const unsigned*)nullptr : amax + (h - 1) * DIM,
                           Pbf, rs, idg,
                           A1T + (size_t)h * DIM * DIM, A2T + (size_t)h * DIM * DIM,
                           v1 + h * DIM, v2 + h * DIM, cc + h * 2,
                           u1 + h * DIM, u2 + h * DIM,
                           amin + h * DIM, amax + h * DIM, outp);
    }
    hipLaunchKernelGGL(k_fin, dim3(512), dim3(256), 0, stream, outp,
                       amin + 3 * DIM, amax + 3 * DIM, (float*)d_out);
}

// Round 5
// 344.119 us; speedup vs baseline: 1.1123x; 1.0145x over previous
//
#include <hip/hip_runtime.h>
#include <hip/hip_bf16.h>
#include <stdint.h>
#include <math.h>

#define NODES 8192
#define EDGES 4096
#define DIM   128
#define HID   256
#define NHEADS 4

using bf8   = __attribute__((ext_vector_type(8))) short;
using f32x4 = __attribute__((ext_vector_type(4))) float;
using i32x4 = __attribute__((ext_vector_type(4))) int;
using s16x4 = __attribute__((ext_vector_type(4))) short;

__device__ __forceinline__ short f2bf(float f) {
    uint32_t u = __float_as_uint(f);
    u += 0x7fffu + ((u >> 16) & 1u);   // RNE
    return (short)(u >> 16);
}
__device__ __forceinline__ float bf2f(short s) {
    return __uint_as_float(((uint32_t)(unsigned short)s) << 16);
}
// order-preserving float<->uint key for atomic min/max
__device__ __forceinline__ unsigned fkey(float f) {
    unsigned u = __float_as_uint(f);
    return (u & 0x80000000u) ? ~u : (u | 0x80000000u);
}
__device__ __forceinline__ float fdec(unsigned k) {
    unsigned u = (k & 0x80000000u) ? (k & 0x7fffffffu) : ~k;
    return __uint_as_float(u);
}

// Fragment-swizzled operand layout for 16x16x32 MFMA:
//   buf[(tile16 * 128 + chunk32) * 512 + lane * 8 .. +7]  (shorts)
// where lane = q*16 + r holds elems [row/col = tile*16 + r][k = chunk*32 + q*8 + j].
// A wave's fragment load is then 64 lanes x 16 B = 1 KB fully contiguous.

// ============ k_init: incidence->swizzled bf16 (+rowsum) , ef->swizzled bf16, x->bf16,
// ============         fused weights/vectors, amin/amax init ============
__global__ __launch_bounds__(256) void k_init(
        const float* __restrict__ inc, short* __restrict__ incB,
        const float* __restrict__ ef, short* __restrict__ efB,
        const float* __restrict__ xf, short* __restrict__ xb,
        const float* __restrict__ Wn, const float* __restrict__ We, const float* __restrict__ Wo,
        const float* __restrict__ Wa, const float* __restrict__ bn, const float* __restrict__ be,
        const float* __restrict__ ba, const float* __restrict__ bo,
        short* __restrict__ A1T, short* __restrict__ A2T,
        float* __restrict__ v1, float* __restrict__ v2,
        float* __restrict__ u1, float* __restrict__ u2, float* __restrict__ cc,
        float* __restrict__ rs, float* __restrict__ idg,
        unsigned* __restrict__ amin, unsigned* __restrict__ amax) {
    __shared__ __align__(16) char smem[17408];
    int b = blockIdx.x, t = threadIdx.x;

    // ---- (1) blocks 0..127: build swizzled efB from ef [4096][128] ----
    if (b < 128) {
        float (*lb)[132] = (float(*)[132])smem;
        int k0 = b * 32;
#pragma unroll
        for (int i = 0; i < 4; ++i) {
            int idx4 = t + i * 256;
            int kk = idx4 >> 5, nq = idx4 & 31;
            f32x4 v = *(const f32x4*)&ef[(size_t)(k0 + kk) * DIM + nq * 4];
            lb[kk][nq * 4 + 0] = v[0]; lb[kk][nq * 4 + 1] = v[1];
            lb[kk][nq * 4 + 2] = v[2]; lb[kk][nq * 4 + 3] = v[3];
        }
        __syncthreads();
#pragma unroll
        for (int i = 0; i < 2; ++i) {
            int o = t + i * 256;
            int nt = o >> 6, lane = o & 63, nr = lane & 15, q = lane >> 4;
            bf8 pk;
#pragma unroll
            for (int j = 0; j < 8; ++j) pk[j] = f2bf(lb[q * 8 + j][nt * 16 + nr]);
            *(bf8*)&efB[((size_t)nt * 128 + b) * 512 + lane * 8] = pk;
        }
        __syncthreads();
    }

    // ---- (2) all blocks: incidence rtile b -> swizzled bf16 + rowsum ----
    {
        float (*la)[132] = (float(*)[132])smem;
        const int row = t >> 4, koff = t & 15;
        const float* ip = inc + (size_t)(b * 16 + row) * EDGES + koff * 8;
        short* ob = incB + (size_t)b * 65536;   // 128 chunks * 512 shorts
        float rsacc = 0.f;
        for (int sc = 0; sc < 32; ++sc) {
            f32x4 v0 = *(const f32x4*)(ip + sc * 128);
            f32x4 v1 = *(const f32x4*)(ip + sc * 128 + 4);
            rsacc += v0[0] + v0[1] + v0[2] + v0[3] + v1[0] + v1[1] + v1[2] + v1[3];
            *(f32x4*)&la[row][koff * 8]     = v0;
            *(f32x4*)&la[row][koff * 8 + 4] = v1;
            __syncthreads();
            {
                int c = t >> 6, lane = t & 63, lr2 = lane & 15, q2 = lane >> 4;
                bf8 pk;
#pragma unroll
                for (int j = 0; j < 8; ++j) pk[j] = f2bf(la[lr2][c * 32 + q2 * 8 + j]);
                *(bf8*)&ob[(size_t)(sc * 4 + c) * 512 + lane * 8] = pk;
            }
            __syncthreads();
        }
        rsacc += __shfl_xor(rsacc, 1); rsacc += __shfl_xor(rsacc, 2);
        rsacc += __shfl_xor(rsacc, 4); rsacc += __shfl_xor(rsacc, 8);
        if (koff == 0) {
            rs[b * 16 + row] = rsacc;
            idg[b * 16 + row] = 1.f / (rsacc + 1e-8f);
        }
    }

    // ---- (3) all blocks: node_features f32 -> bf16 ----
#pragma unroll
    for (int i = 0; i < 2; ++i) {
        int idx = b * 256 + t + i * 131072;
        f32x4 v = *((const f32x4*)xf + idx);
        s16x4 o;
#pragma unroll
        for (int j = 0; j < 4; ++j) o[j] = f2bf(v[j]);
        *((s16x4*)xb + idx) = o;
    }
    // ---- (4) amin/amax init ----
    if (b == 511) {
#pragma unroll
        for (int i = 0; i < 2; ++i) {
            int u = t + i * 256;
            amin[u] = 0xFFFFFFFFu;
            amax[u] = 0u;
        }
    }

    // ---- (5) blocks 128..383: fused weights A1T=(Wn@Wo)^T, A2T=(We@Wo)^T ----
    if (b >= 128 && b < 384) {
        float (*lw)[128][17] = (float(*)[128][17])smem;
        int bb = b - 128;
        int h = bb >> 6, jj = bb & 63;
        int mat = t >> 7, k = t & 127;
        const float* WoH = Wo + (size_t)h * HID * DIM;
        float acc0 = 0.f, acc1 = 0.f;
        for (int mc = 0; mc < 16; ++mc) {
            __syncthreads();
#pragma unroll
            for (int i = 0; i < 4; ++i) {
                int u = t + i * 256;
                int m_ = u >> 9, kk2 = (u >> 2) & 127, qd = u & 3;
                const float* src = (m_ ? We : Wn) + (size_t)h * DIM * HID + (size_t)kk2 * HID + mc * 16 + qd * 4;
                f32x4 val = *(const f32x4*)src;
#pragma unroll
                for (int j2 = 0; j2 < 4; ++j2) lw[m_][kk2][qd * 4 + j2] = val[j2];
            }
            __syncthreads();
#pragma unroll
            for (int mm = 0; mm < 16; ++mm) {
                float a = lw[mat][k][mm];
                int m = mc * 16 + mm;
                acc0 += a * WoH[(size_t)m * DIM + jj];
                acc1 += a * WoH[(size_t)m * DIM + jj + 64];
            }
        }
        short* dst = mat ? A2T : A1T;
        dst[(size_t)h * DIM * DIM + (size_t)jj * DIM + k] = f2bf(acc0);
        dst[(size_t)h * DIM * DIM + (size_t)(jj + 64) * DIM + k] = f2bf(acc1);
    } else if (b >= 384 && b < 388) {
        // ---- (6) fused vectors for head h ----
        float (*lw)[128][17] = (float(*)[128][17])smem;
        int h = b - 384;
        int mat = t >> 7, k = t & 127;
        const float* wa = Wa + (size_t)h * HID;
        float acc = 0.f;
        for (int mc = 0; mc < 16; ++mc) {
            __syncthreads();
#pragma unroll
            for (int i = 0; i < 4; ++i) {
                int u = t + i * 256;
                int m_ = u >> 9, kk2 = (u >> 2) & 127, qd = u & 3;
                const float* src = (m_ ? We : Wn) + (size_t)h * DIM * HID + (size_t)kk2 * HID + mc * 16 + qd * 4;
                f32x4 val = *(const f32x4*)src;
#pragma unroll
                for (int j2 = 0; j2 < 4; ++j2) lw[m_][kk2][qd * 4 + j2] = val[j2];
            }
            __syncthreads();
#pragma unroll
            for (int mm = 0; mm < 16; ++mm) acc += lw[mat][k][mm] * wa[mc * 16 + mm];
        }
        (mat ? v2 : v1)[h * DIM + k] = acc;
        const float* bias = (mat ? be : bn) + (size_t)h * HID;
        const float* WoH = Wo + (size_t)h * HID * DIM;
        float ua = 0.f;
        for (int m = 0; m < HID; ++m) ua += bias[m] * WoH[(size_t)m * DIM + k];
        if (mat) u2[h * DIM + k] = ua;
        else     u1[h * DIM + k] = ua + bo[h * DIM + k];
        if (t < 64) {
            float c = 0.f;
#pragma unroll
            for (int j = 0; j < 4; ++j) { int m = t + j * 64; c += bn[(size_t)h * HID + m] * wa[m]; }
#pragma unroll
            for (int off = 1; off < 64; off <<= 1) c += __shfl_xor(c, off);
            if (t == 0) cc[h * 2 + 0] = c + ba[h];
        } else if (t < 128) {
            int l2 = t - 64;
            float c = 0.f;
#pragma unroll
            for (int j = 0; j < 4; ++j) { int m = l2 + j * 64; c += be[(size_t)h * HID + m] * wa[m]; }
#pragma unroll
            for (int off = 1; off < 64; off <<= 1) c += __shfl_xor(c, off);
            if (l2 == 0) cc[h * 2 + 1] = c;
        }
    }
}

// ============ k_pgemm: P = incidence @ ef on swizzled bf16 operands ============
// 512 blocks = 256 Mtiles(32 rows) x K-split 2; 4 waves each own K=512 (16 chunks).
// Every operand load = 1 KB contiguous per wave. No VALU in the K-loop.
__global__ __launch_bounds__(256) void k_pgemm(const short* __restrict__ incB, const short* __restrict__ efB,
        float* __restrict__ Ppart) {
    __shared__ float red[2][32][129];
    const int t = threadIdx.x;
    const int w = t >> 6, l = t & 63, q = l >> 4, lr = l & 15;
    const int ms = blockIdx.x >> 1, ks = blockIdx.x & 1;
    const int m0 = ms * 32;
    const int c0 = ks * 64 + w * 16;
    const short* ap0 = incB + ((size_t)(ms * 2)     * 128 + c0) * 512 + l * 8;
    const short* ap1 = incB + ((size_t)(ms * 2 + 1) * 128 + c0) * 512 + l * 8;
    const short* bp  = efB  + (size_t)c0 * 512 + l * 8;
    f32x4 acc[2][8];
#pragma unroll
    for (int f = 0; f < 2; ++f)
#pragma unroll
        for (int cb = 0; cb < 8; ++cb) acc[f][cb] = (f32x4){0.f, 0.f, 0.f, 0.f};

    bf8 aA0, aA1, bA[8], aB0, aB1, bB[8];
    aA0 = *(const bf8*)ap0;
    aA1 = *(const bf8*)ap1;
#pragma unroll
    for (int cb = 0; cb < 8; ++cb) bA[cb] = *(const bf8*)(bp + (size_t)cb * 65536);
    for (int s = 0; s < 16; s += 2) {
        if (s + 1 < 16) {
            aB0 = *(const bf8*)(ap0 + (s + 1) * 512);
            aB1 = *(const bf8*)(ap1 + (s + 1) * 512);
#pragma unroll
            for (int cb = 0; cb < 8; ++cb) bB[cb] = *(const bf8*)(bp + (size_t)cb * 65536 + (s + 1) * 512);
        }
#pragma unroll
        for (int cb = 0; cb < 8; ++cb) {
            acc[0][cb] = __builtin_amdgcn_mfma_f32_16x16x32_bf16(aA0, bA[cb], acc[0][cb], 0, 0, 0);
            acc[1][cb] = __builtin_amdgcn_mfma_f32_16x16x32_bf16(aA1, bA[cb], acc[1][cb], 0, 0, 0);
        }
        if (s + 2 < 16) {
            aA0 = *(const bf8*)(ap0 + (s + 2) * 512);
            aA1 = *(const bf8*)(ap1 + (s + 2) * 512);
#pragma unroll
            for (int cb = 0; cb < 8; ++cb) bA[cb] = *(const bf8*)(bp + (size_t)cb * 65536 + (s + 2) * 512);
        }
#pragma unroll
        for (int cb = 0; cb < 8; ++cb) {
            acc[0][cb] = __builtin_amdgcn_mfma_f32_16x16x32_bf16(aB0, bB[cb], acc[0][cb], 0, 0, 0);
            acc[1][cb] = __builtin_amdgcn_mfma_f32_16x16x32_bf16(aB1, bB[cb], acc[1][cb], 0, 0, 0);
        }
    }
    // cross-wave reduce (waves 0+2 -> red[0], 1+3 -> red[1])
    if (w < 2) {
#pragma unroll
        for (int f = 0; f < 2; ++f)
#pragma unroll
            for (int cb = 0; cb < 8; ++cb)
#pragma unroll
                for (int r = 0; r < 4; ++r)
                    red[w][f * 16 + q * 4 + r][cb * 16 + lr] = acc[f][cb][r];
    }
    __syncthreads();
    if (w >= 2) {
#pragma unroll
        for (int f = 0; f < 2; ++f)
#pragma unroll
            for (int cb = 0; cb < 8; ++cb)
#pragma unroll
                for (int r = 0; r < 4; ++r)
                    red[w - 2][f * 16 + q * 4 + r][cb * 16 + lr] += acc[f][cb][r];
    }
    __syncthreads();
    float* gp = Ppart + (size_t)ks * (NODES * DIM) + (size_t)m0 * DIM;
#pragma unroll
    for (int i = 0; i < 4; ++i) {
        int idx = t + i * 256;
        int row = idx >> 5, c4 = (idx & 31) * 4;
        f32x4 o;
#pragma unroll
        for (int j = 0; j < 4; ++j) o[j] = red[0][row][c4 + j] + red[1][row][c4 + j];
        *(f32x4*)&gp[(size_t)row * DIM + c4] = o;
    }
}

// ============ k_comb: Pbf = bf16(Ppart0 + Ppart1) ============
__global__ __launch_bounds__(256) void k_comb(const float* __restrict__ Ppart, short* __restrict__ Pbf) {
    int idx = blockIdx.x * 256 + threadIdx.x;   // 262144 f32x4
    f32x4 a = *((const f32x4*)Ppart + idx);
    f32x4 b = *((const f32x4*)Ppart + 262144 + idx);
    s16x4 o;
#pragma unroll
    for (int j = 0; j < 4; ++j) o[j] = f2bf(a[j] + b[j]);
    *((s16x4*)Pbf + idx) = o;
}

// ============ k_out: per-head fused normalize-in + score + GEMM + atomic minmax ============
__global__ __launch_bounds__(256) void k_out(
        const short* __restrict__ xb,      // head 0 input (bf16) or nullptr
        const float* xf,                   // heads>=1: prev outp f32 (aliases outw)
        const unsigned* __restrict__ aminP, const unsigned* __restrict__ amaxP,
        const short* __restrict__ Pbf, const float* __restrict__ rs, const float* __restrict__ idg,
        const short* __restrict__ W1, const short* __restrict__ W2,
        const float* __restrict__ v1, const float* __restrict__ v2,
        const float* __restrict__ cc, const float* __restrict__ u1, const float* __restrict__ u2,
        unsigned* __restrict__ aminC, unsigned* __restrict__ amaxC,
        float* outw) {
    __shared__ short lx[16][136];
    __shared__ short lp[16][136];
    __shared__ float sv1[128], sv2[128], rsL[16], idL[16], coL[16];
    int t = threadIdx.x, m0 = blockIdx.x * 16;
    int w = t >> 6, l = t & 63, q = l >> 4, lr = l & 15;
    bf8 b1[2][4], b2[2][4];
#pragma unroll
    for (int nf = 0; nf < 2; ++nf) {
        int n = w * 32 + nf * 16 + lr;
#pragma unroll
        for (int kk = 0; kk < 4; ++kk) {
            b1[nf][kk] = *(const bf8*)&W1[(size_t)n * DIM + kk * 32 + q * 8];
            b2[nf][kk] = *(const bf8*)&W2[(size_t)n * DIM + kk * 32 + q * 8];
        }
    }
    {
        int row = t >> 4, c = (t & 15) * 8;
        if (xb) {
            *(i32x4*)&lx[row][c] = *(const i32x4*)&xb[(size_t)(m0 + row) * DIM + c];
        } else {
            f32x4 x0 = *(const f32x4*)&xf[(size_t)(m0 + row) * DIM + c];
            f32x4 x1 = *(const f32x4*)&xf[(size_t)(m0 + row) * DIM + c + 4];
            bf8 pk;
#pragma unroll
            for (int j = 0; j < 8; ++j) {
                float mn = fdec(aminP[c + j]);
                float rv = 1.f / (fdec(amaxP[c + j]) - mn + 1e-8f);
                float xv = (j < 4) ? x0[j] : x1[j - 4];
                pk[j] = f2bf(fmaxf((xv - mn) * rv, 0.f));
            }
            *(bf8*)&lx[row][c] = pk;
        }
        *(i32x4*)&lp[row][c] = *(const i32x4*)&Pbf[(size_t)(m0 + row) * DIM + c];
    }
    if (t < 128) { sv1[t] = v1[t]; sv2[t] = v2[t]; }
    if (t < 16) { rsL[t] = rs[m0 + t]; idL[t] = idg[m0 + t]; }
    __syncthreads();
    if (t < 128) {
        int row = t >> 3, seg = t & 7;
        float id = idL[row];
        float s = 0.f;
#pragma unroll
        for (int j = 0; j < 16; ++j) {
            int c3 = seg * 16 + j;
            s += bf2f(lx[row][c3]) * sv1[c3] + bf2f(lp[row][c3]) * (sv2[c3] * id);
        }
        s += __shfl_xor(s, 1); s += __shfl_xor(s, 2); s += __shfl_xor(s, 4);
        if (seg == 0) {
            float sc = s + cc[0] + rsL[row] * cc[1] * id;
            sc = sc > 0.f ? sc : 0.2f * sc;
            coL[row] = 1.f / (1.f + __expf(-sc));
        }
    }
    f32x4 a1[2] = {{0.f, 0.f, 0.f, 0.f}, {0.f, 0.f, 0.f, 0.f}};
    f32x4 a2[2] = {{0.f, 0.f, 0.f, 0.f}, {0.f, 0.f, 0.f, 0.f}};
#pragma unroll
    for (int kk = 0; kk < 4; ++kk) {
        bf8 xa = *(bf8*)&lx[lr][kk * 32 + q * 8];
        bf8 pa = *(bf8*)&lp[lr][kk * 32 + q * 8];
#pragma unroll
        for (int nf = 0; nf < 2; ++nf) {
            a1[nf] = __builtin_amdgcn_mfma_f32_16x16x32_bf16(xa, b1[nf][kk], a1[nf], 0, 0, 0);
            a2[nf] = __builtin_amdgcn_mfma_f32_16x16x32_bf16(pa, b2[nf][kk], a2[nf], 0, 0, 0);
        }
    }
    __syncthreads();   // coL visible
#pragma unroll
    for (int nf = 0; nf < 2; ++nf) {
        int col = w * 32 + nf * 16 + lr;
        float u1v = u1[col], u2v = u2[col];
        float mnv = 1e30f, mxv = -1e30f;
#pragma unroll
        for (int r = 0; r < 4; ++r) {
            int row = q * 4 + r;
            float cf = coL[row] * idL[row];
            float v = a1[nf][r] + cf * a2[nf][r] + u1v + rsL[row] * cf * u2v;
            outw[(size_t)(m0 + row) * DIM + col] = v;
            mnv = fminf(mnv, v); mxv = fmaxf(mxv, v);
        }
        mnv = fminf(mnv, __shfl_xor(mnv, 16)); mnv = fminf(mnv, __shfl_xor(mnv, 32));
        mxv = fmaxf(mxv, __shfl_xor(mxv, 16)); mxv = fmaxf(mxv, __shfl_xor(mxv, 32));
        if (l < 16) {
            atomicMin(&aminC[col], fkey(mnv));
            atomicMax(&amaxC[col], fkey(mxv));
        }
    }
}

// ============ k_fin: decode last head's minmax, normalize + relu -> d_out ============
__global__ __launch_bounds__(256) void k_fin(const float* __restrict__ outp,
        const unsigned* __restrict__ amin, const unsigned* __restrict__ amax,
        float* __restrict__ dst) {
    __shared__ float smn[128], srv[128];
    int t = threadIdx.x;
    if (t < 128) {
        float mn = fdec(amin[t]);
        smn[t] = mn;
        srv[t] = 1.f / (fdec(amax[t]) - mn + 1e-8f);
    }
    __syncthreads();
#pragma unroll
    for (int i = 0; i < 2; ++i) {
        int idx = blockIdx.x * 256 + t + i * 131072;
        f32x4 v = *((const f32x4*)outp + idx);
        int c0 = (idx & 31) * 4;
#pragma unroll
        for (int j = 0; j < 4; ++j) v[j] = fmaxf((v[j] - smn[c0 + j]) * srv[c0 + j], 0.f);
        *((f32x4*)dst + idx) = v;
    }
}

extern "C" void kernel_launch(void* const* d_in, const int* in_sizes, int n_in,
                              void* d_out, int out_size, void* d_ws, size_t ws_size,
                              hipStream_t stream) {
    const float* nodef = (const float*)d_in[0];
    const float* inc   = (const float*)d_in[1];
    const float* ef    = (const float*)d_in[2];
    const float* Wn    = (const float*)d_in[3];
    const float* bn    = (const float*)d_in[4];
    const float* We    = (const float*)d_in[5];
    const float* be    = (const float*)d_in[6];
    const float* Wa    = (const float*)d_in[7];
    const float* ba    = (const float*)d_in[8];
    const float* Wo    = (const float*)d_in[9];
    const float* bo    = (const float*)d_in[10];

    char* ws = (char*)d_ws;
    float*    outp  = (float*)(ws);                 // 4 MB
    short*    Pbf   = (short*)(ws + 4194304);       // 2 MB
    short*    xb    = (short*)(ws + 6291456);       // 2 MB
    short*    efB   = (short*)(ws + 8388608);       // 1 MB (swizzled)
    short*    incB  = (short*)(ws + 9437184);       // 64 MB (swizzled)
    float*    Ppart = (float*)(ws + 76546048);      // 8 MB
    short*    A1T   = (short*)(ws + 84934656);      // 128 KB
    short*    A2T   = (short*)(ws + 85065728);      // 128 KB
    float*    rs    = (float*)(ws + 85196800);      // 32 KB
    float*    idg   = (float*)(ws + 85229568);      // 32 KB
    float*    v1    = (float*)(ws + 85262336);
    float*    v2    = (float*)(ws + 85264384);
    float*    u1    = (float*)(ws + 85266432);
    float*    u2    = (float*)(ws + 85268480);
    float*    cc    = (float*)(ws + 85270528);
    unsigned* amin  = (unsigned*)(ws + 85272576);   // 4x128
    unsigned* amax  = (unsigned*)(ws + 85274624);   // 4x128

    hipLaunchKernelGGL(k_init, dim3(512), dim3(256), 0, stream,
                       inc, incB, ef, efB, nodef, xb, Wn, We, Wo, Wa, bn, be, ba, bo,
                       A1T, A2T, v1, v2, u1, u2, cc, rs, idg, amin, amax);
    hipLaunchKernelGGL(k_pgemm, dim3(512), dim3(256), 0, stream, incB, efB, Ppart);
    hipLaunchKernelGGL(k_comb, dim3(1024), dim3(256), 0, stream, Ppart, Pbf);

    for (int h = 0; h < NHEADS; ++h) {
        hipLaunchKernelGGL(k_out, dim3(512), dim3(256), 0, stream,
                           (h == 0) ? xb : (const short*)nullptr,
                           (h == 0) ? (const float*)nullptr : outp,
                           (h == 0) ? (const unsigned*)nullptr : amin + (h - 1) * DIM,
                           (h == 0) ? (const unsigned*)nullptr : amax + (h - 1) * DIM,
                           Pbf, rs, idg,
                           A1T + (size_t)h * DIM * DIM, A2T + (size_t)h * DIM * DIM,
                           v1 + h * DIM, v2 + h * DIM, cc + h * 2,
                           u1 + h * DIM, u2 + h * DIM,
                           amin + h * DIM, amax + h * DIM, outp);
    }
    hipLaunchKernelGGL(k_fin, dim3(512), dim3(256), 0, stream, outp,
                       amin + 3 * DIM, amax + 3 * DIM, (float*)d_out);
}